// Round 11
// baseline (175.161 us; speedup 1.0000x reference)
//
#include <hip/hip_runtime.h>
#include <stdint.h>

#define OUT_F   4096
#define IN_F    11008
#define BATCH   64
#define NSUP    43                  // super-blocks per row
#define SB_ROW  344                 // sub-blocks per row
#define IPR     5504                // int32 elements per weight row
#define NKS     8                   // K-splits: 3 of 6 sups + 5 of 5 sups = 43
#define NCB     64                  // row-blocks of 64 -> 512 blocks = 2/CU
#define XP_BYTES   (344 * 256 * 16)                 // 1,409,024
#define SCMN_BYTES (NSUP * 4096 * 16)               // 2,818,048
#define DDM_BYTES  (NSUP * 4096 * 8)                // 1,409,024
#define PW_OFF     (XP_BYTES + SCMN_BYTES + DDM_BYTES)
#define PW_REAL    ((size_t)OUT_F * IN_F / 2)       // 22,544,384 B dense nibbles
#define PART_OFF   (PW_OFF + PW_REAL)
#define PART_BYTES ((size_t)NKS * BATCH * OUT_F * 4)
#define WS_FULL    (PART_OFF + PART_BYTES)
#define REPACK_BLKS 11008           // one block per gs = g*43+sup; 256 gs-groups * 43 sups

typedef __attribute__((ext_vector_type(8))) short  short8;
typedef __attribute__((ext_vector_type(4))) float  floatx4;
typedef __attribute__((ext_vector_type(4))) int    intx4;

__device__ __forceinline__ unsigned pack_bf16(float f0, float f1) {
    // result = [bf16(f0) in low16, bf16(f1) in high16]
    return __builtin_amdgcn_perm(__float_as_uint(f1), __float_as_uint(f0), 0x07060302u);
}

__device__ __forceinline__ unsigned low_bytes4(intx4 d) {
    // gather low byte of each of 4 ints into one dword: [d.x b0, d.y b0, d.z b0, d.w b0]
    unsigned p01 = __builtin_amdgcn_perm((unsigned)d.y, (unsigned)d.x, 0x00000400u);
    unsigned p23 = __builtin_amdgcn_perm((unsigned)d.w, (unsigned)d.z, 0x00000400u);
    return __builtin_amdgcn_perm(p23, p01, 0x05040100u);
}

// ---- fused prep ----
// blocks [0, 11008): repack weights to dense nibbles in MFMA-B fragment order:
//   pw dword index = ((g*43 + sup)*64 + lane)*8 + st,  lane = hi*16+lo,
//   holding quants of row g*16+lo, k = sup*256 + st*32 + hi*8 + [0,8)
// blocks [11008,11352): x fragments.  blocks [11352,12040): scale metadata.
__global__ __launch_bounds__(256) void prep_kernel(const float* __restrict__ x,
                                                   const int* __restrict__ packed,
                                                   const int* __restrict__ scales,
                                                   const int* __restrict__ mins,
                                                   const float* __restrict__ dd,
                                                   const float* __restrict__ dmn,
                                                   intx4* __restrict__ xp,
                                                   int2* __restrict__ pw,
                                                   intx4* __restrict__ scmn_p,
                                                   float2* __restrict__ ddm_p) {
    if (blockIdx.x < REPACK_BLKS) {
        const int gid  = blockIdx.x * 256 + threadIdx.x;
        const int st2  = gid & 3;                           // st pair
        const int lane = (gid >> 2) & 63;
        const int gs   = gid >> 8;                          // g*43 + sup
        const int lo   = lane & 15, hi = lane >> 4;
        const int row  = (gs / 43) * 16 + lo;
        const int sup  = gs % 43;
        const int base = row * IPR + sup * 128 + st2 * 32 + hi * 4;
        intx4 d0 = *(const intx4*)(packed + base);          // st = 2*st2
        intx4 d1 = *(const intx4*)(packed + base + 16);     // st = 2*st2+1
        int2 o;
        o.x = (int)low_bytes4(d0);
        o.y = (int)low_bytes4(d1);
        pw[gid] = o;                                        // coalesced 8B store
    } else if (blockIdx.x < REPACK_BLKS + 344) {
        const int ksb = blockIdx.x - REPACK_BLKS;
        const int mt  = threadIdx.x >> 6;
        const int l   = threadIdx.x & 63;
        const int lo  = l & 15, hi = l >> 4;
        const float* src = x + (mt * 16 + lo) * IN_F + ksb * 32 + hi * 8;
        floatx4 a0 = *(const floatx4*)src;
        floatx4 a1 = *(const floatx4*)(src + 4);
        intx4 r;
        r.x = pack_bf16(a0.x, a0.y);
        r.y = pack_bf16(a0.z, a0.w);
        r.z = pack_bf16(a1.x, a1.y);
        r.w = pack_bf16(a1.z, a1.w);
        xp[(mt * 344 + ksb) * 64 + l] = r;
    } else {
        const int tg  = (blockIdx.x - REPACK_BLKS - 344) * 256 + threadIdx.x;
        const int row = tg / 43;
        const int sup = tg - row * 43;
        const intx4 s0 = *(const intx4*)(scales + row * SB_ROW + sup * 8);
        const intx4 s1 = *(const intx4*)(scales + row * SB_ROW + sup * 8 + 4);
        const intx4 m0 = *(const intx4*)(mins   + row * SB_ROW + sup * 8);
        const intx4 m1 = *(const intx4*)(mins   + row * SB_ROW + sup * 8 + 4);
        intx4 o;
        o.x = s0.x | (s0.y << 8) | (s0.z << 16) | (s0.w << 24);
        o.y = s1.x | (s1.y << 8) | (s1.z << 16) | (s1.w << 24);
        o.z = m0.x | (m0.y << 8) | (m0.z << 16) | (m0.w << 24);
        o.w = m1.x | (m1.y << 8) | (m1.z << 16) | (m1.w << 24);
        scmn_p[sup * 4096 + row] = o;
        float2 dp;
        dp.x = dd[row * NSUP + sup];
        dp.y = dmn[row * NSUP + sup];
        ddm_p[sup * 4096 + row] = dp;
    }
}

__global__ __launch_bounds__(256) void init_out_kernel(const float* __restrict__ bias,
                                                       float* __restrict__ out) {
    int i = blockIdx.x * 256 + threadIdx.x;
    out[i] = bias[i & (OUT_F - 1)];
}

__global__ __launch_bounds__(256) void reduce_kernel(const float* __restrict__ part,
                                                     const float* __restrict__ bias,
                                                     float* __restrict__ out) {
    const int i = blockIdx.x * 256 + threadIdx.x;
    float s = bias[i & (OUT_F - 1)];
    #pragma unroll
    for (int k = 0; k < NKS; ++k) s += part[(size_t)k * (BATCH * OUT_F) + i];
    out[i] = s;
}

// block = 64 out-rows x 64 batch x K-split. Weights: dense fragment-order
// nibbles, 2 coalesced b128 loads per wave per sup. x fragments via LDS.
template<bool USE_PART>
__global__ __launch_bounds__(256, 2) void qlin_main(
    const intx4*  __restrict__ xp,
    const intx4*  __restrict__ pw4,      // dense nibbles, 16B granules
    const intx4*  __restrict__ scmn_p,
    const float2* __restrict__ ddm_p,
    float*        __restrict__ part,
    float*        __restrict__ out)
{
    __shared__ intx4  xfs[2048];       // 32KB x fragments [mt*512 + st*64 + l]
    __shared__ intx4  scs[64];         // packed sc/mn per row
    __shared__ float2 dds[64];         // d, dmin per row

    const int ks  = blockIdx.x & 7;
    const int nb  = blockIdx.x >> 3;          // 0..63
    const int tid = threadIdx.x;
    const int w   = tid >> 6;
    const int l   = tid & 63;
    const int lo  = l & 15, hi = l >> 4;

    const int sup0 = ks < 3 ? 6 * ks : 18 + 5 * (ks - 3);
    const int nsup = ks < 3 ? 6 : 5;
    const int g    = nb * 4 + w;              // this wave's row-group of 16

    floatx4 acc[4];
    #pragma unroll
    for (int mt = 0; mt < 4; ++mt) acc[mt] = (floatx4)0.0f;

    const int myrow = w * 16 + lo;

    #pragma unroll 1
    for (int s = 0; s < nsup; ++s) {
        const int sup = sup0 + s;
        __syncthreads();                      // prev sup's readers done

        // ---- weights: 2 coalesced 16B loads per lane (8 dwords = 8 steps) ----
        const intx4* wp = pw4 + ((size_t)(g * 43 + sup) * 64 + l) * 2;
        intx4 w8a = wp[0];
        intx4 w8b = wp[1];

        // ---- x fragments + metadata staged to LDS ----
        intx4 xtmp[8];
        const intx4* xsrc = xp + sup * 512;
        #pragma unroll
        for (int i = 0; i < 8; ++i) {
            const int idx = i * 256 + tid;
            xtmp[i] = xsrc[(idx >> 9) * 22016 + (idx & 511)];
        }
        intx4 sctv; float2 ddv;
        if (tid < 64)       sctv = scmn_p[sup * 4096 + nb * 64 + tid];
        else if (tid < 128) ddv  = ddm_p[sup * 4096 + nb * 64 + (tid - 64)];

        #pragma unroll
        for (int i = 0; i < 8; ++i)
            xfs[i * 256 + tid] = xtmp[i];
        if (tid < 64)       scs[tid] = sctv;
        else if (tid < 128) dds[tid - 64] = ddv;
        __syncthreads();

        // ---- per-sup dequant constants ----
        const intx4  sv = scs[myrow];
        const float2 dp = dds[myrow];
        const float a945 = dp.x * (1.0f / 945.0f);
        const float a63  = dp.x * (1.0f / 63.0f);

        // ---- 8 K-steps ----
        #pragma unroll
        for (int st = 0; st < 8; ++st) {
            const unsigned u = (unsigned)((st < 4) ? w8a[st] : w8b[st - 4]);
            const int scw = (st < 4) ? sv.x : sv.y;
            const int mnw = (st < 4) ? sv.z : sv.w;
            const float A = a945 * (float)((scw >> ((st & 3) * 8)) & 255);
            const float B = fmaf(a63, (float)((mnw >> ((st & 3) * 8)) & 255), dp.y);

            union { intx4 i; short8 s8; } uw;
            uw.i.x = pack_bf16(fmaf((float)(u & 15u), A, B),
                               fmaf((float)((u >> 4) & 15u), A, B));
            uw.i.y = pack_bf16(fmaf((float)((u >> 8) & 15u), A, B),
                               fmaf((float)((u >> 12) & 15u), A, B));
            uw.i.z = pack_bf16(fmaf((float)((u >> 16) & 15u), A, B),
                               fmaf((float)((u >> 20) & 15u), A, B));
            uw.i.w = pack_bf16(fmaf((float)((u >> 24) & 15u), A, B),
                               fmaf((float)(u >> 28), A, B));

            union { intx4 i; short8 s8; } u0, u1, u2, u3;
            u0.i = xfs[0 * 512 + st * 64 + l];
            u1.i = xfs[1 * 512 + st * 64 + l];
            u2.i = xfs[2 * 512 + st * 64 + l];
            u3.i = xfs[3 * 512 + st * 64 + l];
            acc[0] = __builtin_amdgcn_mfma_f32_16x16x32_bf16(u0.s8, uw.s8, acc[0], 0, 0, 0);
            acc[1] = __builtin_amdgcn_mfma_f32_16x16x32_bf16(u1.s8, uw.s8, acc[1], 0, 0, 0);
            acc[2] = __builtin_amdgcn_mfma_f32_16x16x32_bf16(u2.s8, uw.s8, acc[2], 0, 0, 0);
            acc[3] = __builtin_amdgcn_mfma_f32_16x16x32_bf16(u3.s8, uw.s8, acc[3], 0, 0, 0);
        }
    }

    // ---- epilogue: D col = lane&15 -> out-row o; row-in-tile = hi*4+r -> batch m ----
    const int o = nb * 64 + myrow;
    if (USE_PART) {
        float* p0 = part + (size_t)ks * (BATCH * OUT_F) + o;
        #pragma unroll
        for (int mt = 0; mt < 4; ++mt) {
            #pragma unroll
            for (int r = 0; r < 4; ++r)
                p0[(mt * 16 + hi * 4 + r) * OUT_F] = acc[mt][r];
        }
    } else {
        #pragma unroll
        for (int mt = 0; mt < 4; ++mt) {
            #pragma unroll
            for (int r = 0; r < 4; ++r)
                atomicAdd(out + (mt * 16 + hi * 4 + r) * OUT_F + o, acc[mt][r]);
        }
    }
}

extern "C" void kernel_launch(void* const* d_in, const int* in_sizes, int n_in,
                              void* d_out, int out_size, void* d_ws, size_t ws_size,
                              hipStream_t stream) {
    (void)in_sizes; (void)n_in; (void)out_size;
    const float* x      = (const float*)d_in[0];
    const int*   packed = (const int*)d_in[1];
    const float* d      = (const float*)d_in[2];
    const float* dmin   = (const float*)d_in[3];
    const int*   scales = (const int*)d_in[4];
    const int*   mins   = (const int*)d_in[5];
    const float* bias   = (const float*)d_in[6];
    float* out = (float*)d_out;

    intx4*  xp     = (intx4*)d_ws;
    intx4*  scmn_p = (intx4*)((char*)d_ws + XP_BYTES);
    float2* ddm_p  = (float2*)((char*)d_ws + XP_BYTES + SCMN_BYTES);
    int2*   pw     = (int2*)((char*)d_ws + PW_OFF);
    float*  part   = (float*)((char*)d_ws + PART_OFF);
    const bool has_part = ws_size >= (size_t)WS_FULL;

    prep_kernel<<<REPACK_BLKS + 344 + 688, 256, 0, stream>>>(
        x, packed, scales, mins, d, dmin, xp, pw, scmn_p, ddm_p);

    if (has_part) {
        qlin_main<true><<<NCB * NKS, 256, 0, stream>>>(
            xp, (const intx4*)pw, scmn_p, ddm_p, part, out);
        reduce_kernel<<<(BATCH * OUT_F) / 256, 256, 0, stream>>>(part, bias, out);
    } else {
        init_out_kernel<<<(BATCH * OUT_F) / 256, 256, 0, stream>>>(bias, out);
        qlin_main<false><<<NCB * NKS, 256, 0, stream>>>(
            xp, (const intx4*)pw, scmn_p, ddm_p, part, out);
    }
}